// Round 19
// baseline (122.246 us; speedup 1.0000x reference)
//
#include <hip/hip_runtime.h>
#include <hip/hip_bf16.h>
#include <cstdint>
#include <cstddef>

#define NV    8192   // nodes
#define KIN   512    // in features
#define MOUT  128    // out features
#define LOG2E 1.4426950408889634f

typedef __attribute__((ext_vector_type(4))) float f32x4;
typedef __attribute__((ext_vector_type(8))) short short8;

__device__ __forceinline__ float elu1(float x) { return x > 0.f ? x : expm1f(x); }

__device__ __forceinline__ unsigned int pkbf2(float a, float b) {
  union { __hip_bfloat162 h2; unsigned int u; } r;
  r.h2 = __float22bfloat162_rn(make_float2(a, b));
  return r.u;
}

// ---------------- kernel 1: wh1/wh2 (log2-scaled) + fragB (bf16, MFMA-fragment order) ----------------
// 16-row blocks (512 total, >=2/CU). fragB element (j=jt*64+ks*32+lg*8+e, c=cgf*16+l15).
__global__ __launch_bounds__(256) void k_wh(const float* __restrict__ h,
                                            const float* __restrict__ w,
                                            const float* __restrict__ a1,
                                            const float* __restrict__ a2,
                                            unsigned short* __restrict__ fragB,
                                            float* __restrict__ wh1,
                                            float* __restrict__ wh2) {
  __shared__ __align__(16) float hT[64][18];    // [k][row], 16 rows + 2 pad
  __shared__ __align__(16) float wT[64][128];   // [k][col]
  const int t = threadIdx.x;
  const int row0 = blockIdx.x * 16;
  const int hrow = t & 15, hkq = t >> 4;        // h-load: row, k-quad
  const int wc = t >> 1, whalf = t & 1;         // w-load
  const int cg = t & 31, rg = t >> 5;           // gemm: col-group(4), row-group(2)
  const int c0 = cg * 4, r0 = rg * 2;
  float acc[2][4] = {};

  for (int kt = 0; kt < 8; ++kt) {
    const int k0 = kt * 64;
    __syncthreads();
    {
      const float4 hv = *(const float4*)&h[(size_t)(row0 + hrow) * KIN + k0 + hkq * 4];
      hT[hkq * 4 + 0][hrow] = hv.x;
      hT[hkq * 4 + 1][hrow] = hv.y;
      hT[hkq * 4 + 2][hrow] = hv.z;
      hT[hkq * 4 + 3][hrow] = hv.w;
    }
#pragma unroll
    for (int mv = 0; mv < 8; ++mv) {
      const float4 wv4 = *(const float4*)&w[(size_t)wc * KIN + k0 + whalf * 32 + mv * 4];
      wT[whalf * 32 + mv * 4 + 0][wc] = wv4.x;
      wT[whalf * 32 + mv * 4 + 1][wc] = wv4.y;
      wT[whalf * 32 + mv * 4 + 2][wc] = wv4.z;
      wT[whalf * 32 + mv * 4 + 3][wc] = wv4.w;
    }
    __syncthreads();
#pragma unroll 8
    for (int kk = 0; kk < 64; ++kk) {
      const float2 hv = *(const float2*)&hT[kk][r0];
      const float4 wv4 = *(const float4*)&wT[kk][c0];
      const float hvv[2] = {hv.x, hv.y};
      const float wvv[4] = {wv4.x, wv4.y, wv4.z, wv4.w};
#pragma unroll
      for (int i = 0; i < 2; ++i)
#pragma unroll
        for (int j = 0; j < 4; ++j)
          acc[i][j] = fmaf(hvv[i], wvv[j], acc[i][j]);
    }
  }

  // fragB store straight from accumulators (lg reduction modulo 32-row ks-block — R16 fix).
  {
    const size_t jt = (size_t)(row0 >> 6);
    const int ks = (row0 >> 5) & 1;
    const int lg = (((row0 & 31) + rg * 2) >> 3);   // 0..3
    const int cgf = cg >> 2;
    unsigned int* fB32 = (unsigned int*)fragB;
    const size_t ubase = (((jt * 8 + cgf) * 2 + ks) * 64 + lg * 16) * 4 + (rg & 3);
#pragma unroll
    for (int j = 0; j < 4; ++j) {
      const int l15 = (cg & 3) * 4 + j;
      fB32[ubase + (size_t)l15 * 4] = pkbf2(acc[0][j], acc[1][j]);
    }
  }

  const float4 a1v = *(const float4*)&a1[c0];
  const float4 a2v = *(const float4*)&a2[c0];
#pragma unroll
  for (int i = 0; i < 2; ++i) {
    float s1 = acc[i][0] * a1v.x + acc[i][1] * a1v.y + acc[i][2] * a1v.z + acc[i][3] * a1v.w;
    float s2 = acc[i][0] * a2v.x + acc[i][1] * a2v.y + acc[i][2] * a2v.z + acc[i][3] * a2v.w;
#pragma unroll
    for (int off = 16; off > 0; off >>= 1) {
      s1 += __shfl_down(s1, off, 32);
      s2 += __shfl_down(s2, off, 32);
    }
    if (cg == 0) {
      wh1[row0 + r0 + i] = s1 * LOG2E;
      wh2[row0 + r0 + i] = s2 * LOG2E;
    }
  }
}

// ---------------- kernel 2: adj-pack + attention partials (R9 structure, VERBATIM) ----------------
// Measured optimum across 18 rounds: ~103 us, VGPR exactly 64 (the occupancy cliff: 64 ->
// 8 waves/SIMD, 65+ -> 4; R16's +12-VGPR epilogue cost 80 us). Do NOT add state here.
__global__ __launch_bounds__(256) void k_attn_p(const unsigned short* __restrict__ fragB,
                                                const int* __restrict__ adj,
                                                const float* __restrict__ wh1l,
                                                const float* __restrict__ wh2l,
                                                float* __restrict__ out_p,
                                                float* __restrict__ psum_p) {
  __shared__ char smask[64 * 136];
  const int t = threadIdx.x;
  const int i0 = blockIdx.x * 64;
  const int jbase = blockIdx.y * 1024;    // ntiles = 16
  const int lane = t & 63, wv = t >> 6;
  const int ih = wv & 1, ch = wv >> 1;
  const int l15 = lane & 15, lg = lane >> 4;

  const int* abase = adj + (size_t)i0 * NV + jbase;

  // ---- phase 0: pack adj slice -> LDS bitmask (wave owns 16 rows, 4 KB sequential bursts) ----
  for (int rr = 0; rr < 16; ++rr) {
    const int r = wv * 16 + rr;
    const int* rp = abase + (size_t)r * NV + lane * 16;
    unsigned int m = 0;
#pragma unroll
    for (int p = 0; p < 4; ++p) {
      const int4 v = *(const int4*)(rp + p * 4);
      m |= ((unsigned)(v.x & 1) << (4 * p))     | ((unsigned)(v.y & 1) << (4 * p + 1)) |
           ((unsigned)(v.z & 1) << (4 * p + 2)) | ((unsigned)(v.w & 1) << (4 * p + 3));
    }
    *(unsigned short*)&smask[r * 136 + (lane >> 2) * 8 + (lane & 3) * 2] = (unsigned short)m;
  }
  __syncthreads();

  // ---- phase 1 ----
  const int rb = ih * 32;
  const float wh1a = wh1l[i0 + rb + l15];
  const float wh1b = wh1l[i0 + rb + 16 + l15];
  const char* mrowa = smask + (rb + l15) * 136;
  const char* mrowb = smask + (rb + 16 + l15) * 136;
  const unsigned short* bptr = fragB + (size_t)(jbase >> 6) * 8192 + ch * 4096 + lane * 8;
  const float* w2ptr = wh2l + jbase + lg * 8;

  f32x4 acc[2][4] = {};
  f32x4 accs[2] = {};
  short8 onesf;
#pragma unroll
  for (int e = 0; e < 8; ++e) onesf[e] = (short)0x3F80;  // bf16 1.0

  uint2 m2a = *(const uint2*)&mrowa[0];
  uint2 m2b = *(const uint2*)&mrowb[0];
  short8 bf[8];
#pragma unroll
  for (int ks = 0; ks < 2; ++ks)
#pragma unroll
    for (int cgl = 0; cgl < 4; ++cgl)
      bf[ks * 4 + cgl] = *(const short8*)(bptr + cgl * 1024 + ks * 512);
  bptr += 8192;

  for (int it = 0; it < 16; ++it) {
    const unsigned int m16a = ((m2a.x >> (8 * lg)) & 0xFFu) |
                              (((m2a.y >> (8 * lg)) & 0xFFu) << 8);
    const unsigned int m16b = ((m2b.x >> (8 * lg)) & 0xFFu) |
                              (((m2b.y >> (8 * lg)) & 0xFFu) << 8);
    const float4 wq0 = *(const float4*)(w2ptr);
    const float4 wq1 = *(const float4*)(w2ptr + 4);
    const float4 wq2 = *(const float4*)(w2ptr + 32);
    const float4 wq3 = *(const float4*)(w2ptr + 36);
    w2ptr += 64;

    short8 afa[2], afb[2];
#pragma unroll
    for (int ks = 0; ks < 2; ++ks) {
      const float4 wa = ks ? wq2 : wq0;
      const float4 wb = ks ? wq3 : wq1;
      const float w2v[8] = {wa.x, wa.y, wa.z, wa.w, wb.x, wb.y, wb.z, wb.w};
      union { short8 s8; unsigned int u[4]; } pka, pkb;
#pragma unroll
      for (int e = 0; e < 4; ++e) {
        const float x0 = wh1a + w2v[2 * e];
        const float x1 = wh1a + w2v[2 * e + 1];
        const float y0 = wh1b + w2v[2 * e];
        const float y1 = wh1b + w2v[2 * e + 1];
        const float lx0 = fmaxf(x0, 0.01f * x0);
        const float lx1 = fmaxf(x1, 0.01f * x1);
        const float ly0 = fmaxf(y0, 0.01f * y0);
        const float ly1 = fmaxf(y1, 0.01f * y1);
        float px0 = __builtin_amdgcn_exp2f(lx0);
        float px1 = __builtin_amdgcn_exp2f(lx1);
        float py0 = __builtin_amdgcn_exp2f(ly0);
        float py1 = __builtin_amdgcn_exp2f(ly1);
        px0 = ((m16a >> (ks * 8 + 2 * e)) & 1u) ? px0 : 0.f;
        px1 = ((m16a >> (ks * 8 + 2 * e + 1)) & 1u) ? px1 : 0.f;
        py0 = ((m16b >> (ks * 8 + 2 * e)) & 1u) ? py0 : 0.f;
        py1 = ((m16b >> (ks * 8 + 2 * e + 1)) & 1u) ? py1 : 0.f;
        pka.u[e] = pkbf2(px0, px1);
        pkb.u[e] = pkbf2(py0, py1);
      }
      afa[ks] = pka.s8;
      afb[ks] = pkb.s8;
    }
    if (it + 1 < 16) {
      m2a = *(const uint2*)&mrowa[(it + 1) * 8];
      m2b = *(const uint2*)&mrowb[(it + 1) * 8];
    }
#pragma unroll
    for (int ks = 0; ks < 2; ++ks) {
      acc[0][0] = __builtin_amdgcn_mfma_f32_16x16x32_bf16(afa[ks], bf[ks * 4 + 0], acc[0][0], 0, 0, 0);
      acc[0][1] = __builtin_amdgcn_mfma_f32_16x16x32_bf16(afa[ks], bf[ks * 4 + 1], acc[0][1], 0, 0, 0);
      acc[0][2] = __builtin_amdgcn_mfma_f32_16x16x32_bf16(afa[ks], bf[ks * 4 + 2], acc[0][2], 0, 0, 0);
      acc[0][3] = __builtin_amdgcn_mfma_f32_16x16x32_bf16(afa[ks], bf[ks * 4 + 3], acc[0][3], 0, 0, 0);
      accs[0]   = __builtin_amdgcn_mfma_f32_16x16x32_bf16(afa[ks], onesf, accs[0], 0, 0, 0);
      acc[1][0] = __builtin_amdgcn_mfma_f32_16x16x32_bf16(afb[ks], bf[ks * 4 + 0], acc[1][0], 0, 0, 0);
      acc[1][1] = __builtin_amdgcn_mfma_f32_16x16x32_bf16(afb[ks], bf[ks * 4 + 1], acc[1][1], 0, 0, 0);
      acc[1][2] = __builtin_amdgcn_mfma_f32_16x16x32_bf16(afb[ks], bf[ks * 4 + 2], acc[1][2], 0, 0, 0);
      acc[1][3] = __builtin_amdgcn_mfma_f32_16x16x32_bf16(afb[ks], bf[ks * 4 + 3], acc[1][3], 0, 0, 0);
      accs[1]   = __builtin_amdgcn_mfma_f32_16x16x32_bf16(afb[ks], onesf, accs[1], 0, 0, 0);
    }
    if (it + 1 < 16) {
#pragma unroll
      for (int ks = 0; ks < 2; ++ks)
#pragma unroll
        for (int cgl = 0; cgl < 4; ++cgl)
          bf[ks * 4 + cgl] = *(const short8*)(bptr + cgl * 1024 + ks * 512);
      bptr += 8192;
    }
  }

  // psum via ones-column: lane(l15=0,lg) reg r holds rowsum[rg*16 + lg*4 + r]
  if (ch == 0 && l15 == 0) {
#pragma unroll
    for (int rg = 0; rg < 2; ++rg)
#pragma unroll
      for (int r = 0; r < 4; ++r)
        psum_p[(size_t)blockIdx.y * NV + i0 + rb + rg * 16 + lg * 4 + r] = accs[rg][r];
  }

  // unnormalized partial tiles (C/D: col=l15, row=lg*4+r)
#pragma unroll
  for (int rg = 0; rg < 2; ++rg) {
    const size_t ob = ((size_t)blockIdx.y * NV + i0 + rb + rg * 16) * MOUT + ch * 64;
#pragma unroll
    for (int cgl = 0; cgl < 4; ++cgl)
#pragma unroll
      for (int r = 0; r < 4; ++r)
        out_p[ob + (size_t)(lg * 4 + r) * MOUT + cgl * 16 + l15] = acc[rg][cgl][r];
  }
}

// ---------------- kernel 3: combine partials, normalize, ELU (2 tiles/thread for ILP) ----------------
// R18 fixed slab-loop serialization (runtime S -> unrolled 8); still 3 TB/s because each
// tiny block issued only 8 loads then exited (latency-amortization-poor). Now each thread
// handles TWO float4 groups half-an-array apart: 16 independent out_p loads + 2 psum-group
// loads in flight, 512 blocks. Memory-bound; VGPR ~80 harmless here (no cliff sensitivity).
__global__ __launch_bounds__(256) void k_comb(const float* __restrict__ out_p,
                                              const float* __restrict__ psum_p,
                                              float* __restrict__ out) {
  const int base = (blockIdx.x * 256 + threadIdx.x) * 4;
  const int HALF = NV * MOUT / 2;
  const int idx0 = base, idx1 = base + HALF;
  const int n0 = idx0 >> 7, n1 = idx1 >> 7;   // MOUT = 128

  float4 v0[8], v1[8];
#pragma unroll
  for (int s = 0; s < 8; ++s) {
    v0[s] = *(const float4*)&out_p[(size_t)s * NV * MOUT + idx0];
    v1[s] = *(const float4*)&out_p[(size_t)s * NV * MOUT + idx1];
  }
  float d0[8], d1[8];
#pragma unroll
  for (int s = 0; s < 8; ++s) {
    d0[s] = psum_p[(size_t)s * NV + n0];
    d1[s] = psum_p[(size_t)s * NV + n1];
  }

  const float den0 = ((d0[0] + d0[1]) + (d0[2] + d0[3])) + ((d0[4] + d0[5]) + (d0[6] + d0[7]));
  const float den1 = ((d1[0] + d1[1]) + (d1[2] + d1[3])) + ((d1[4] + d1[5]) + (d1[6] + d1[7]));

  float4 a0, a1v;
  a0.x = ((v0[0].x + v0[1].x) + (v0[2].x + v0[3].x)) + ((v0[4].x + v0[5].x) + (v0[6].x + v0[7].x));
  a0.y = ((v0[0].y + v0[1].y) + (v0[2].y + v0[3].y)) + ((v0[4].y + v0[5].y) + (v0[6].y + v0[7].y));
  a0.z = ((v0[0].z + v0[1].z) + (v0[2].z + v0[3].z)) + ((v0[4].z + v0[5].z) + (v0[6].z + v0[7].z));
  a0.w = ((v0[0].w + v0[1].w) + (v0[2].w + v0[3].w)) + ((v0[4].w + v0[5].w) + (v0[6].w + v0[7].w));
  a1v.x = ((v1[0].x + v1[1].x) + (v1[2].x + v1[3].x)) + ((v1[4].x + v1[5].x) + (v1[6].x + v1[7].x));
  a1v.y = ((v1[0].y + v1[1].y) + (v1[2].y + v1[3].y)) + ((v1[4].y + v1[5].y) + (v1[6].y + v1[7].y));
  a1v.z = ((v1[0].z + v1[1].z) + (v1[2].z + v1[3].z)) + ((v1[4].z + v1[5].z) + (v1[6].z + v1[7].z));
  a1v.w = ((v1[0].w + v1[1].w) + (v1[2].w + v1[3].w)) + ((v1[4].w + v1[5].w) + (v1[6].w + v1[7].w));

  const float inv0 = 1.f / den0;
  const float inv1 = 1.f / den1;
  float4 o0, o1;
  o0.x = elu1(a0.x * inv0);  o0.y = elu1(a0.y * inv0);
  o0.z = elu1(a0.z * inv0);  o0.w = elu1(a0.w * inv0);
  o1.x = elu1(a1v.x * inv1); o1.y = elu1(a1v.y * inv1);
  o1.z = elu1(a1v.z * inv1); o1.w = elu1(a1v.w * inv1);
  *(float4*)&out[idx0] = o0;
  *(float4*)&out[idx1] = o1;
}

extern "C" void kernel_launch(void* const* d_in, const int* in_sizes, int n_in,
                              void* d_out, int out_size, void* d_ws, size_t ws_size,
                              hipStream_t stream) {
  const float* h  = (const float*)d_in[0];
  const int* adj  = (const int*)d_in[1];
  const float* w  = (const float*)d_in[2];
  const float* a1 = (const float*)d_in[3];
  const float* a2 = (const float*)d_in[4];
  float* out = (float*)d_out;

  char* ws = (char*)d_ws;
  // layout: [fragB 2MB][wh1 32KB][wh2 32KB][psum_p 256KB][out_p 8*4MB]
  unsigned short* fragB = (unsigned short*)ws;
  size_t off = (size_t)MOUT * NV * 2;
  float* wh1 = (float*)(ws + off); off += (size_t)NV * 4;
  float* wh2 = (float*)(ws + off); off += (size_t)NV * 4;
  float* psum_p = (float*)(ws + off); off += (size_t)8 * NV * 4;
  float* out_p = (float*)(ws + off);

  k_wh<<<NV / 16, 256, 0, stream>>>(h, w, a1, a2, fragB, wh1, wh2);
  k_attn_p<<<dim3(NV / 64, 8), 256, 0, stream>>>(fragB, adj, wh1, wh2, out_p, psum_p);
  k_comb<<<(NV * MOUT / 8) / 256, 256, 0, stream>>>(out_p, psum_p, out);
}